// Round 2
// 628.550 us; speedup vs baseline: 1.1665x; 1.1665x over previous
//
#include <hip/hip_runtime.h>
#include <math.h>

// Problem constants (fixed by the reference)
#define BATCH 16
#define SMAX 4096
#define DMODEL 4096
#define NH 32
#define NKV 8
#define NREP 4
#define DH 128
#define QKCOLS 5120   // 4096 (q) + 1024 (k)
#define NCHUNK 8      // s-dimension split for flash-decode
#define CHUNK 512     // positions per chunk
#define TILE 64       // positions per LDS tile
#define NCH 64        // d-chunks for gemv partials
#define GD 64         // d rows per gemv chunk

// ---------------------------------------------------------------------------
// GEMV partials: part[ch][b][col] = sum_{d in chunk} in[b][d] * w[d][col]
// Each lane owns 2 consecutive cols (one float2 weight load per d-row).
// x is read wave-uniformly (L1-broadcast). No LDS, no barriers.
// grid: (totC/512 col-blocks, 64 d-chunks), block 256.
// ---------------------------------------------------------------------------
__global__ __launch_bounds__(256) void gemv_part(
    const float* __restrict__ in,   // [16][4096]
    const float* __restrict__ w1, int c1,
    const float* __restrict__ w2, int c2,
    float* __restrict__ part)       // [NCH][16][c1+c2]
{
    const int t = threadIdx.x;
    const int col = blockIdx.x * 512 + t * 2;
    const int totC = c1 + c2;
    const int d0 = blockIdx.y * GD;

    const float* w; int stride, wc;
    if (col < c1) { w = w1; stride = c1; wc = col; }
    else          { w = w2; stride = c2; wc = col - c1; }
    const float* wp = w + (size_t)d0 * stride + wc;

    float2 acc[BATCH];
#pragma unroll
    for (int b = 0; b < BATCH; ++b) acc[b] = make_float2(0.f, 0.f);

#pragma unroll 4
    for (int i = 0; i < GD; ++i) {
        const float2 wv = *(const float2*)(wp + (size_t)i * stride);
#pragma unroll
        for (int b = 0; b < BATCH; ++b) {
            const float xv = in[(size_t)b * DMODEL + d0 + i];  // wave-uniform
            acc[b].x = fmaf(wv.x, xv, acc[b].x);
            acc[b].y = fmaf(wv.y, xv, acc[b].y);
        }
    }
    const size_t base = (size_t)blockIdx.y * BATCH;
#pragma unroll
    for (int b = 0; b < BATCH; ++b)
        *(float2*)&part[(base + b) * totC + col] = acc[b];
}

// ---------------------------------------------------------------------------
// Reduce 64 partials + apply RoPE (interleaved even/odd pairs). 40960 pairs.
// ---------------------------------------------------------------------------
__global__ __launch_bounds__(256) void rope_reduce(
    const float* __restrict__ part,  // [64][16][5120]
    const float* __restrict__ fcos, const float* __restrict__ fsin,
    float* __restrict__ xqk)         // [16][5120]
{
    int g = blockIdx.x * 256 + threadIdx.x;      // pair id: 16*2560
    int b = g / 2560;
    int po = g % 2560;
    float e = 0.f, o = 0.f;
    const float* p = part + (size_t)b * QKCOLS + 2 * po;
#pragma unroll 8
    for (int ch = 0; ch < NCH; ++ch) {
        float2 v = *(const float2*)(p + (size_t)ch * BATCH * QKCOLS);
        e += v.x; o += v.y;
    }
    int i = po & 63;                 // pair index within a head (DH/2 = 64)
    float c = fcos[i], s = fsin[i];
    xqk[(size_t)b * QKCOLS + 2 * po]     = e * c - o * s;
    xqk[(size_t)b * QKCOLS + 2 * po + 1] = e * s + o * c;
}

// ---------------------------------------------------------------------------
// Flash-decode attention partial (V == K!). grid (8 chunks, 8 kv, 16 b),
// block 256 = 4 waves, wave r owns rep r.
// Row-per-lane scores on XOR-swizzled LDS (conflict-free ds_read_b128),
// p broadcast via LDS (no shuffles in score/PV), async reg staging of the
// next tile under compute. Writes (acc[128], m, l) per record.
// ---------------------------------------------------------------------------
__global__ __launch_bounds__(256, 4) void attn_part_kernel(
    const float* __restrict__ cache_k,  // [16][4096][8][128]
    const float* __restrict__ xqk,      // [16][5120]
    const int* __restrict__ sp,
    float* __restrict__ out)            // [b][kv][chunk][r][130]
{
    const int chunk = blockIdx.x;
    const int kv = blockIdx.y;
    const int b = blockIdx.z;
    const int t = threadIdx.x;
    const int dl = t & 63;              // lane: owns score row dl, out cols 2dl..2dl+1
    const int r = t >> 6;               // wave = rep
    const int start_pos = sp[0];

    __shared__ float k_lds[TILE * DH];      // 32 KB, XOR-swizzled 16B slots
    __shared__ float q_lds[NREP * DH];      // 2 KB
    __shared__ float p_lds[NREP * TILE];    // 1 KB

    const float* xknew = xqk + (size_t)b * QKCOLS + DMODEL + kv * DH;
    const float* kbase = cache_k + ((size_t)b * SMAX * NKV + kv) * DH;
    const float scale = 0.08838834764831845f;   // 1/sqrt(128)

    // q for all 4 reps of this kv head, pre-scaled
    {
        const float* qp0 = xqk + (size_t)b * QKCOLS + (kv * NREP) * DH;
        q_lds[t]       = qp0[t] * scale;
        q_lds[256 + t] = qp0[256 + t] * scale;
    }

    float4 st[8];

#define STAGE(TT) do {                                                        \
        const int s_b_ = chunk * CHUNK + (TT) * TILE;                         \
        _Pragma("unroll")                                                     \
        for (int it = 0; it < 8; ++it) {                                      \
            int f_ = it * 256 + t;                                            \
            int row_ = f_ >> 5;                                               \
            int c4_ = f_ & 31;                                                \
            int s_ = s_b_ + row_;                                             \
            const float* src_ = (s_ == start_pos) ? (xknew + 4 * c4_)         \
                              : (kbase + (size_t)s_ * (NKV * DH) + 4 * c4_);  \
            st[it] = *(const float4*)src_;                                    \
        }                                                                     \
    } while (0)

#define KWRITE() do {                                                         \
        _Pragma("unroll")                                                     \
        for (int it = 0; it < 8; ++it) {                                      \
            int f_ = it * 256 + t;                                            \
            int row_ = f_ >> 5;                                               \
            int c4_ = f_ & 31;                                                \
            *(float4*)&k_lds[row_ * DH + ((c4_ ^ (row_ & 7)) << 2)] = st[it]; \
        }                                                                     \
    } while (0)

    STAGE(0);
    KWRITE();
    __syncthreads();

    float m_run = -1e30f, l_run = 0.f;
    float ax = 0.f, ay = 0.f;
    const float* qh = q_lds + r * DH;
    const float* krow = k_lds + dl * DH;
    const int sw = dl & 7;              // swizzle key for own row
    const int c4o = dl >> 1;            // float4 slot containing col 2*dl
    const int o2 = (2 * dl) & 3;        // offset within that slot

    for (int tt = 0; tt < CHUNK / TILE; ++tt) {
        if (tt < CHUNK / TILE - 1) STAGE(tt + 1);   // loads in flight under compute

        const int s_base = chunk * CHUNK + tt * TILE;

        // ---- scores: lane dl computes full dot for row dl (4 indep chains) ----
        float c0 = 0.f, c1 = 0.f, c2 = 0.f, c3 = 0.f;
#pragma unroll 4
        for (int i = 0; i < 32; ++i) {
            const float4 q4 = *(const float4*)(qh + 4 * i);                 // uniform bcast
            const float4 k4 = *(const float4*)(krow + ((i ^ sw) << 2));     // conflict-free
            c0 = fmaf(q4.x, k4.x, c0);
            c1 = fmaf(q4.y, k4.y, c1);
            c2 = fmaf(q4.z, k4.z, c2);
            c3 = fmaf(q4.w, k4.w, c3);
        }
        float score = (c0 + c1) + (c2 + c3);
        if (s_base + dl > start_pos) score = -1e30f;

        // ---- online softmax (wave-private: one rep per wave) ----
        float m_tile = score;
#pragma unroll
        for (int m = 1; m < 64; m <<= 1)
            m_tile = fmaxf(m_tile, __shfl_xor(m_tile, m, 64));
        float m_new = fmaxf(m_run, m_tile);
        float alpha = __expf(m_run - m_new);
        float p = __expf(score - m_new);
        float psum = p;
#pragma unroll
        for (int m = 1; m < 64; m <<= 1)
            psum += __shfl_xor(psum, m, 64);
        l_run = l_run * alpha + psum;
        ax *= alpha; ay *= alpha;
        m_run = m_new;

        p_lds[r * TILE + dl] = p;
        __syncthreads();                // p visible (also keeps waves phase-locked)

        // ---- PV accumulate (V == K): p broadcast from LDS, rows uniform ----
#pragma unroll 4
        for (int j4 = 0; j4 < 16; ++j4) {
            const float4 pj = *(const float4*)&p_lds[r * TILE + 4 * j4];    // uniform bcast
#define PVROW(JJ, PV) do {                                                    \
            const int rw_ = 4 * j4 + (JJ);                                    \
            const float2 k2_ = *(const float2*)&k_lds[rw_ * DH +              \
                                   ((c4o ^ (rw_ & 7)) << 2) + o2];            \
            ax = fmaf((PV), k2_.x, ax);                                       \
            ay = fmaf((PV), k2_.y, ay);                                       \
        } while (0)
            PVROW(0, pj.x);
            PVROW(1, pj.y);
            PVROW(2, pj.z);
            PVROW(3, pj.w);
#undef PVROW
        }
        __syncthreads();                // everyone done reading k_lds

        if (tt < CHUNK / TILE - 1) {
            KWRITE();                   // next tile into LDS
            __syncthreads();
        }
    }

    float* rec = out + ((((size_t)b * NKV + kv) * NCHUNK + chunk) * NREP + r) * 130;
    rec[2 * dl] = ax;
    rec[2 * dl + 1] = ay;
    if (dl == 0) { rec[128] = m_run; rec[129] = l_run; }
#undef STAGE
#undef KWRITE
}

// ---------------------------------------------------------------------------
// Combine chunk partials -> attn_out[b][h*128+d]. grid (32 h, 16 b), 128 thr.
// ---------------------------------------------------------------------------
__global__ __launch_bounds__(128) void attn_combine(
    const float* __restrict__ part, float* __restrict__ attn_out)
{
    const int hq = blockIdx.x;
    const int b = blockIdx.y;
    const int kv = hq >> 2, r = hq & 3;
    const int d = threadIdx.x;
    float m_c[NCHUNK], l_c[NCHUNK];
    float M = -1e30f;
#pragma unroll
    for (int c = 0; c < NCHUNK; ++c) {
        const float* rec = part + ((((size_t)b * NKV + kv) * NCHUNK + c) * NREP + r) * 130;
        m_c[c] = rec[128]; l_c[c] = rec[129];
        M = fmaxf(M, m_c[c]);
    }
    float num = 0.f, den = 0.f;
#pragma unroll
    for (int c = 0; c < NCHUNK; ++c) {
        const float* rec = part + ((((size_t)b * NKV + kv) * NCHUNK + c) * NREP + r) * 130;
        float w = __expf(m_c[c] - M);
        num = fmaf(w, rec[d], num);
        den = fmaf(w, l_c[c], den);
    }
    attn_out[(size_t)b * DMODEL + hq * DH + d] = num / den;
}

// ---------------------------------------------------------------------------
// Final reduce of output-projection partials -> d_out (fp32)
// ---------------------------------------------------------------------------
__global__ __launch_bounds__(256) void reduce_out(
    const float* __restrict__ part, float* __restrict__ out)
{
    int g = blockIdx.x * 256 + threadIdx.x;   // 0..65535
    int b = g >> 12, o = g & 4095;
    float s = 0.f;
#pragma unroll 8
    for (int ch = 0; ch < NCH; ++ch)
        s += part[((size_t)ch * BATCH + b) * DMODEL + o];
    out[g] = s;
}

extern "C" void kernel_launch(void* const* d_in, const int* in_sizes, int n_in,
                              void* d_out, int out_size, void* d_ws, size_t ws_size,
                              hipStream_t stream) {
    const float* x       = (const float*)d_in[0];
    const float* cache_k = (const float*)d_in[1];
    // d_in[2] = cache_v: UNUSED (reference's PV einsum uses keys)
    const float* wq      = (const float*)d_in[3];
    const float* wk      = (const float*)d_in[4];
    // d_in[5] = wv: UNUSED
    const float* wo      = (const float*)d_in[6];
    const float* fcos    = (const float*)d_in[7];
    const float* fsin    = (const float*)d_in[8];
    const int*   sp      = (const int*)d_in[9];
    float* out = (float*)d_out;
    float* ws  = (float*)d_ws;

    // ws layout (floats); part_qk region reused for part_out (disjoint lifetime)
    float* part_qk   = ws;                        // 64*16*5120 = 5,242,880
    float* xqk       = part_qk + 5242880;         // 16*5120    =    81,920
    float* attn_part = xqk + 81920;               // 16*8*8*4*130 = 532,480
    float* attn_out  = attn_part + 532480;        // 16*4096    =    65,536
    float* part_out  = part_qk;                   // 64*16*4096 = 4,194,304 (reuse)

    // 1) x @ [wq | wk] partials (64 d-chunks of 64)
    gemv_part<<<dim3(QKCOLS / 512, NCH), 256, 0, stream>>>(x, wq, 4096, wk, 1024, part_qk);
    // 2) reduce + RoPE
    rope_reduce<<<160, 256, 0, stream>>>(part_qk, fcos, fsin, xqk);
    // 3) flash-decode attention partials (single pass over cache_k, V==K)
    attn_part_kernel<<<dim3(NCHUNK, NKV, BATCH), 256, 0, stream>>>(cache_k, xqk, sp, attn_part);
    // 4) combine chunks
    attn_combine<<<dim3(NH, BATCH), 128, 0, stream>>>(attn_part, attn_out);
    // 5) attn_out @ wo partials
    gemv_part<<<dim3(DMODEL / 512, NCH), 256, 0, stream>>>(attn_out, wo, 4096, nullptr, 0, part_out);
    // 6) final reduce -> d_out
    reduce_out<<<256, 256, 0, stream>>>(part_out, out);
}